// Round 5
// baseline (528.042 us; speedup 1.0000x reference)
//
#include <hip/hip_runtime.h>
#include <hip/hip_bf16.h>

// GraphSAGE on MI355X — round 5: fused aggregation+GEMM.
// Pipeline: memset, k_prep (count+cvt+wprep), scan x3, scatter,
// k_fused128 (L0), k_fused128 (L1), proj-GEMM, k_fused64 (L2). 10 dispatches.
// Each fused block aggregates its own 128 rows into LDS, then MFMAs.

#define NFEAT 128

typedef __attribute__((ext_vector_type(8))) short short8;
typedef __attribute__((ext_vector_type(4))) float floatx4;

__device__ __forceinline__ float bf_lo(unsigned u) { return __uint_as_float(u << 16); }
__device__ __forceinline__ float bf_hi(unsigned u) { return __uint_as_float(u & 0xffff0000u); }
__device__ __forceinline__ ushort f2bf(float f) {
    __hip_bfloat16 h = __float2bfloat16(f);
    return *(ushort*)&h;
}
__device__ __forceinline__ unsigned pack2(float a, float b) {
    return (unsigned)f2bf(a) | ((unsigned)f2bf(b) << 16);
}

// ---------------- combined prep: degree count (4-way split) + x->bf16 + weight prep ----------------

__global__ __launch_bounds__(256) void k_prep(
    const int* __restrict__ dst, int* __restrict__ deg4, int* __restrict__ rnk,
    int E, int NN,
    const float* __restrict__ X, ushort* __restrict__ X16, int n2,
    const float* __restrict__ Ws0, const float* __restrict__ Wn0,
    const float* __restrict__ Ws1, const float* __restrict__ Wn1,
    const float* __restrict__ Ws2, const float* __restrict__ Wn2,
    ushort* __restrict__ Wt0, ushort* __restrict__ Wt1, ushort* __restrict__ Wt2,
    int e4b, int cvtb) {
    int b = blockIdx.x, t = threadIdx.x;
    if (b < e4b) {
        int base = (b * 256 + t) * 4;
        if (base + 4 <= E) {
            int4 d4 = *(const int4*)(dst + base);
            int4 r4;
            r4.x = atomicAdd(&deg4[0 * NN + d4.x], 1);
            r4.y = atomicAdd(&deg4[1 * NN + d4.y], 1);
            r4.z = atomicAdd(&deg4[2 * NN + d4.z], 1);
            r4.w = atomicAdd(&deg4[3 * NN + d4.w], 1);
            *(int4*)(rnk + base) = r4;
        } else {
            for (int e = base; e < E; ++e)
                rnk[e] = atomicAdd(&deg4[(e & 3) * NN + dst[e]], 1);
        }
    } else if (b < e4b + cvtb) {
        int i = (b - e4b) * 256 + t;
        if (i < n2) {
            float2 v = ((const float2*)X)[i];
            ((unsigned*)X16)[i] = pack2(v.x, v.y);
        }
    } else {
        int idx = (b - e4b - cvtb) * 256 + t;
        if (idx < 32768) {
            int n = idx >> 8, k = idx & 255;
            Wt0[idx] = f2bf(k < 128 ? Ws0[k * 128 + n] : Wn0[(k - 128) * 128 + n]);
        } else if (idx < 65536) {
            int l = idx - 32768, n = l >> 8, k = l & 255;
            Wt1[l] = f2bf(k < 128 ? Ws1[k * 128 + n] : Wn1[(k - 128) * 128 + n]);
        } else if (idx < 81920) {
            int l = idx - 65536, n = l >> 8, k = l & 255;
            Wt2[l] = f2bf(k < 128 ? Ws2[k * 64 + n] : Wn2[(k - 128) * 64 + n]);
        }
    }
}

// ---------------- scans (unchanged) ----------------

__global__ void k_scan1(const int* __restrict__ deg4, int* __restrict__ off1,
                        int* __restrict__ off2, int* __restrict__ off3,
                        int* __restrict__ ptrA, int* __restrict__ partials, int NN) {
    __shared__ int sh[256];
    int t = threadIdx.x;
    int i = blockIdx.x * 256 + t;
    int d0 = 0, d1 = 0, d2 = 0, d3 = 0;
    if (i < NN) {
        d0 = deg4[i]; d1 = deg4[NN + i]; d2 = deg4[2 * NN + i]; d3 = deg4[3 * NN + i];
        off1[i] = d0; off2[i] = d0 + d1; off3[i] = d0 + d1 + d2;
    }
    int v = d0 + d1 + d2 + d3;
    sh[t] = v;
    __syncthreads();
#pragma unroll
    for (int off = 1; off < 256; off <<= 1) {
        int x = (t >= off) ? sh[t - off] : 0;
        __syncthreads();
        sh[t] += x;
        __syncthreads();
    }
    if (i < NN) ptrA[i] = sh[t] - v;
    if (t == 255) partials[blockIdx.x] = sh[255];
}

__global__ void k_scan2(int* __restrict__ partials, int nb) {
    __shared__ int sh[256];
    int t = threadIdx.x;
    int v = (t < nb) ? partials[t] : 0;
    sh[t] = v;
    __syncthreads();
#pragma unroll
    for (int off = 1; off < 256; off <<= 1) {
        int x = (t >= off) ? sh[t - off] : 0;
        __syncthreads();
        sh[t] += x;
        __syncthreads();
    }
    if (t < nb) partials[t] = sh[t] - v;
}

__global__ void k_scan3(int* __restrict__ ptrA, const int* __restrict__ partials,
                        int NN, int E) {
    int i = blockIdx.x * 256 + threadIdx.x;
    if (i < NN) ptrA[i] += partials[blockIdx.x];
    if (i == 0) ptrA[NN] = E;
}

__global__ __launch_bounds__(256) void k_scatter(const int* __restrict__ src,
                                                 const int* __restrict__ dst,
                                                 const int* __restrict__ rnk,
                                                 const int* __restrict__ ptrA,
                                                 const int* __restrict__ off1,
                                                 const int* __restrict__ off2,
                                                 const int* __restrict__ off3,
                                                 int* __restrict__ csr, int E) {
    int base = (blockIdx.x * 256 + threadIdx.x) * 4;
    if (base + 4 <= E) {
        int4 d4 = *(const int4*)(dst + base);
        int4 r4 = *(const int4*)(rnk + base);
        int4 s4 = *(const int4*)(src + base);
        csr[ptrA[d4.x] + r4.x] = s4.x;
        csr[ptrA[d4.y] + off1[d4.y] + r4.y] = s4.y;
        csr[ptrA[d4.z] + off2[d4.z] + r4.z] = s4.z;
        csr[ptrA[d4.w] + off3[d4.w] + r4.w] = s4.w;
    } else {
        for (int e = base; e < E; ++e) {
            int d = dst[e], q = e & 3;
            int off = (q == 0) ? 0 : ((q == 1) ? off1[d] : ((q == 2) ? off2[d] : off3[d]));
            csr[ptrA[d] + off + rnk[e]] = src[e];
        }
    }
}

// ---------------- fused layer kernel (128-wide): agg into LDS, then MFMA ----------------
// C = relu([H | mean-agg(H)] @ Wt^T + b), bf16 out. 256 thr, BM=128, K=256.

__global__ __launch_bounds__(256) void k_fused128(
    const ushort* __restrict__ H, const int* __restrict__ ptrA,
    const int* __restrict__ csr, const ushort* __restrict__ Wt,
    const float* __restrict__ bias, ushort* __restrict__ Cout, int M) {
    constexpr int LDA = 40;    // staging row stride (ushorts)
    constexpr int LDG = 136;   // AggT row stride (ushorts): start banks 4(r+q)%32
    __shared__ ushort AggT[128 * LDG];
    __shared__ ushort Asl[128 * LDA];
    __shared__ ushort Bsl[128 * LDA];

    int t = threadIdx.x, lane = t & 63, wid = t >> 6;
    int m0 = blockIdx.x * 128;
    int sub = lane >> 4, fl = lane & 15;   // 16 lanes/row, 4 edge slots

    // phase 1: each wave mean-aggregates 32 nodes into AggT (bf16)
    for (int i = 0; i < 32; ++i) {
        int node = m0 + wid * 32 + i;      // wave-uniform
        if (node >= M) break;
        int beg = ptrA[node], end = ptrA[node + 1];
        float acc[8] = {};
        int e = beg + sub;
        for (; e + 4 < end; e += 8) {      // 2 rows in flight per lane
            int r0 = csr[e], r1 = csr[e + 4];
            uint4 v0 = *(const uint4*)(H + (size_t)r0 * NFEAT + fl * 8);
            uint4 v1 = *(const uint4*)(H + (size_t)r1 * NFEAT + fl * 8);
            acc[0] += bf_lo(v0.x) + bf_lo(v1.x); acc[1] += bf_hi(v0.x) + bf_hi(v1.x);
            acc[2] += bf_lo(v0.y) + bf_lo(v1.y); acc[3] += bf_hi(v0.y) + bf_hi(v1.y);
            acc[4] += bf_lo(v0.z) + bf_lo(v1.z); acc[5] += bf_hi(v0.z) + bf_hi(v1.z);
            acc[6] += bf_lo(v0.w) + bf_lo(v1.w); acc[7] += bf_hi(v0.w) + bf_hi(v1.w);
        }
        for (; e < end; e += 4) {
            int r = csr[e];
            uint4 v = *(const uint4*)(H + (size_t)r * NFEAT + fl * 8);
            acc[0] += bf_lo(v.x); acc[1] += bf_hi(v.x);
            acc[2] += bf_lo(v.y); acc[3] += bf_hi(v.y);
            acc[4] += bf_lo(v.z); acc[5] += bf_hi(v.z);
            acc[6] += bf_lo(v.w); acc[7] += bf_hi(v.w);
        }
#pragma unroll
        for (int off = 16; off < 64; off <<= 1)
#pragma unroll
            for (int j = 0; j < 8; ++j) acc[j] += __shfl_xor(acc[j], off, 64);
        if (sub == 0) {
            int d = end - beg;
            float inv = (d > 0) ? 1.0f / (float)d : 0.0f;
            uint4 u;
            u.x = pack2(acc[0] * inv, acc[1] * inv);
            u.y = pack2(acc[2] * inv, acc[3] * inv);
            u.z = pack2(acc[4] * inv, acc[5] * inv);
            u.w = pack2(acc[6] * inv, acc[7] * inv);
            *(uint4*)(&AggT[(wid * 32 + i) * LDG + fl * 8]) = u;
        }
    }

    // phase 2: MFMA, K=256 (kb<4: H self-half staged; kb>=4: AggT direct)
    int wm = wid & 1, wn = wid >> 1;
    int l15 = lane & 15, quad = lane >> 4;
    floatx4 acc[4][4] = {};

    for (int kb = 0; kb < 8; ++kb) {
        __syncthreads();
        if (kb < 4) {
#pragma unroll
            for (int id = t; id < 128 * 4; id += 256) {
                int r = id >> 2, p = id & 3;
                uint4 v = make_uint4(0, 0, 0, 0);
                if (m0 + r < M) v = *(const uint4*)(H + (size_t)(m0 + r) * NFEAT + kb * 32 + p * 8);
                *(uint4*)(&Asl[r * LDA + p * 8]) = v;
            }
        }
#pragma unroll
        for (int id = t; id < 128 * 4; id += 256) {
            int r = id >> 2, p = id & 3;
            uint4 v = *(const uint4*)(Wt + (size_t)r * 256 + kb * 32 + p * 8);
            *(uint4*)(&Bsl[r * LDA + p * 8]) = v;
        }
        __syncthreads();

        short8 a[4], b[4];
#pragma unroll
        for (int mt = 0; mt < 4; ++mt) {
            int row = wm * 64 + mt * 16 + l15;
            a[mt] = (kb < 4)
                ? *(const short8*)(&Asl[row * LDA + quad * 8])
                : *(const short8*)(&AggT[row * LDG + (kb - 4) * 32 + quad * 8]);
        }
#pragma unroll
        for (int nt = 0; nt < 4; ++nt)
            b[nt] = *(const short8*)(&Bsl[(wn * 64 + nt * 16 + l15) * LDA + quad * 8]);
#pragma unroll
        for (int mt = 0; mt < 4; ++mt)
#pragma unroll
            for (int nt = 0; nt < 4; ++nt)
                acc[mt][nt] = __builtin_amdgcn_mfma_f32_16x16x32_bf16(a[mt], b[nt], acc[mt][nt], 0, 0, 0);
    }

#pragma unroll
    for (int mt = 0; mt < 4; ++mt) {
        int mbase = m0 + wm * 64 + mt * 16 + quad * 4;
#pragma unroll
        for (int nt = 0; nt < 4; ++nt) {
            int col = wn * 64 + nt * 16 + l15;
            float bv = bias[col];
#pragma unroll
            for (int r = 0; r < 4; ++r) {
                int m = mbase + r;
                if (m < M) {
                    float v = fmaxf(acc[mt][nt][r] + bv, 0.f);
                    Cout[(size_t)m * NFEAT + col] = f2bf(v);
                }
            }
        }
    }
}

// ---------------- proj GEMM (layer 2): G2 = Hb @ Wn2^T, bf16 out ----------------

template <int BN, int NKB>
__global__ __launch_bounds__(64 * 2 * (BN / 64)) void gemm_proj(
    const ushort* __restrict__ Hs, const ushort* __restrict__ Wt, int ldw,
    ushort* __restrict__ Cout, int M) {
    constexpr int WN = BN / 64;
    constexpr int NTHR = 64 * 2 * WN;
    constexpr int LDA = 40;
    __shared__ ushort Asl[128 * LDA];
    __shared__ ushort Bsl[BN * LDA];

    int t = threadIdx.x, lane = t & 63, wid = t >> 6;
    int wm = wid & 1, wn = wid >> 1;
    int l15 = lane & 15, quad = lane >> 4;
    int m0 = blockIdx.x * 128;

    floatx4 acc[4][4] = {};

    for (int kb = 0; kb < NKB; ++kb) {
        __syncthreads();
#pragma unroll
        for (int id = t; id < 128 * 4; id += NTHR) {
            int r = id >> 2, p = id & 3;
            uint4 v = make_uint4(0, 0, 0, 0);
            if (m0 + r < M) v = *(const uint4*)(Hs + (size_t)(m0 + r) * NFEAT + kb * 32 + p * 8);
            *(uint4*)(&Asl[r * LDA + p * 8]) = v;
        }
#pragma unroll
        for (int id = t; id < BN * 4; id += NTHR) {
            int r = id >> 2, p = id & 3;
            uint4 v = *(const uint4*)(Wt + (size_t)r * ldw + kb * 32 + p * 8);
            *(uint4*)(&Bsl[r * LDA + p * 8]) = v;
        }
        __syncthreads();

        short8 a[4], b[4];
#pragma unroll
        for (int mt = 0; mt < 4; ++mt)
            a[mt] = *(const short8*)(&Asl[(wm * 64 + mt * 16 + l15) * LDA + quad * 8]);
#pragma unroll
        for (int nt = 0; nt < 4; ++nt)
            b[nt] = *(const short8*)(&Bsl[(wn * 64 + nt * 16 + l15) * LDA + quad * 8]);
#pragma unroll
        for (int mt = 0; mt < 4; ++mt)
#pragma unroll
            for (int nt = 0; nt < 4; ++nt)
                acc[mt][nt] = __builtin_amdgcn_mfma_f32_16x16x32_bf16(a[mt], b[nt], acc[mt][nt], 0, 0, 0);
    }

#pragma unroll
    for (int mt = 0; mt < 4; ++mt) {
        int mbase = m0 + wm * 64 + mt * 16 + quad * 4;
#pragma unroll
        for (int nt = 0; nt < 4; ++nt) {
            int col = wn * 64 + nt * 16 + l15;
#pragma unroll
            for (int r = 0; r < 4; ++r) {
                int m = mbase + r;
                if (m < M) Cout[(size_t)m * BN + col] = f2bf(acc[mt][nt][r]);
            }
        }
    }
}

// ---------------- fused layer 2: gather-mean G2 (fp32 LDS) + Hb@Ws2 + b2 -> fp32 out ----------------

__global__ __launch_bounds__(128) void k_fused64(
    const ushort* __restrict__ G2, const ushort* __restrict__ Hb,
    const int* __restrict__ ptrA, const int* __restrict__ csr,
    const ushort* __restrict__ Wt2, const float* __restrict__ bias,
    float* __restrict__ Cout, int M) {
    constexpr int LDA = 40;
    constexpr int LDF = 68;    // fp32 row stride
    __shared__ float AggF[128 * LDF];
    __shared__ ushort Asl[128 * LDA];
    __shared__ ushort Bsl[64 * LDA];

    int t = threadIdx.x, lane = t & 63, wid = t >> 6;   // 2 waves
    int m0 = blockIdx.x * 128;
    int sub = lane >> 3, fl = lane & 7;   // 8 lanes/row, 8 edge slots

    for (int i = 0; i < 64; ++i) {
        int node = m0 + wid * 64 + i;
        if (node >= M) break;
        int beg = ptrA[node], end = ptrA[node + 1];
        float acc[8] = {};
        int e = beg + sub;
        for (; e + 8 < end; e += 16) {
            int r0 = csr[e], r1 = csr[e + 8];
            uint4 v0 = *(const uint4*)(G2 + (size_t)r0 * 64 + fl * 8);
            uint4 v1 = *(const uint4*)(G2 + (size_t)r1 * 64 + fl * 8);
            acc[0] += bf_lo(v0.x) + bf_lo(v1.x); acc[1] += bf_hi(v0.x) + bf_hi(v1.x);
            acc[2] += bf_lo(v0.y) + bf_lo(v1.y); acc[3] += bf_hi(v0.y) + bf_hi(v1.y);
            acc[4] += bf_lo(v0.z) + bf_lo(v1.z); acc[5] += bf_hi(v0.z) + bf_hi(v1.z);
            acc[6] += bf_lo(v0.w) + bf_lo(v1.w); acc[7] += bf_hi(v0.w) + bf_hi(v1.w);
        }
        for (; e < end; e += 8) {
            int r = csr[e];
            uint4 v = *(const uint4*)(G2 + (size_t)r * 64 + fl * 8);
            acc[0] += bf_lo(v.x); acc[1] += bf_hi(v.x);
            acc[2] += bf_lo(v.y); acc[3] += bf_hi(v.y);
            acc[4] += bf_lo(v.z); acc[5] += bf_hi(v.z);
            acc[6] += bf_lo(v.w); acc[7] += bf_hi(v.w);
        }
#pragma unroll
        for (int off = 8; off < 64; off <<= 1)
#pragma unroll
            for (int j = 0; j < 8; ++j) acc[j] += __shfl_xor(acc[j], off, 64);
        if (sub == 0) {
            int d = end - beg;
            float inv = (d > 0) ? 1.0f / (float)d : 0.0f;
            float* dp = &AggF[(wid * 64 + i) * LDF + fl * 8];
#pragma unroll
            for (int j = 0; j < 8; ++j) dp[j] = acc[j] * inv;
        }
    }

    int wm = wid;
    int l15 = lane & 15, quad = lane >> 4;
    floatx4 acc2[4][4] = {};

    for (int kb = 0; kb < 4; ++kb) {
        __syncthreads();
#pragma unroll
        for (int id = t; id < 128 * 4; id += 128) {
            int r = id >> 2, p = id & 3;
            uint4 v = make_uint4(0, 0, 0, 0);
            if (m0 + r < M) v = *(const uint4*)(Hb + (size_t)(m0 + r) * NFEAT + kb * 32 + p * 8);
            *(uint4*)(&Asl[r * LDA + p * 8]) = v;
        }
#pragma unroll
        for (int id = t; id < 64 * 4; id += 128) {
            int r = id >> 2, p = id & 3;
            uint4 v = *(const uint4*)(Wt2 + (size_t)r * 256 + kb * 32 + p * 8);
            *(uint4*)(&Bsl[r * LDA + p * 8]) = v;
        }
        __syncthreads();

        short8 a[4], b[4];
#pragma unroll
        for (int mt = 0; mt < 4; ++mt)
            a[mt] = *(const short8*)(&Asl[(wm * 64 + mt * 16 + l15) * LDA + quad * 8]);
#pragma unroll
        for (int nt = 0; nt < 4; ++nt)
            b[nt] = *(const short8*)(&Bsl[(nt * 16 + l15) * LDA + quad * 8]);
#pragma unroll
        for (int mt = 0; mt < 4; ++mt)
#pragma unroll
            for (int nt = 0; nt < 4; ++nt)
                acc2[mt][nt] = __builtin_amdgcn_mfma_f32_16x16x32_bf16(a[mt], b[nt], acc2[mt][nt], 0, 0, 0);
    }

#pragma unroll
    for (int mt = 0; mt < 4; ++mt) {
        int mloc = wm * 64 + mt * 16 + quad * 4;
#pragma unroll
        for (int nt = 0; nt < 4; ++nt) {
            int col = nt * 16 + l15;
            float bv = bias[col];
#pragma unroll
            for (int r = 0; r < 4; ++r) {
                int m = m0 + mloc + r;
                if (m < M)
                    Cout[(size_t)m * 64 + col] =
                        acc2[mt][nt][r] + bv + AggF[(mloc + r) * LDF + col];
            }
        }
    }
}

// ---------------- launch ----------------

static inline size_t align_up(size_t x) { return (x + 255) & ~(size_t)255; }

extern "C" void kernel_launch(void* const* d_in, const int* in_sizes, int n_in,
                              void* d_out, int out_size, void* d_ws, size_t ws_size,
                              hipStream_t stream) {
    const float* x   = (const float*)d_in[0];
    const int*   src = (const int*)d_in[1];
    const int*   dst = (const int*)d_in[2];
    const float* Ws0 = (const float*)d_in[3];
    const float* Wn0 = (const float*)d_in[4];
    const float* b0  = (const float*)d_in[5];
    const float* Ws1 = (const float*)d_in[6];
    const float* Wn1 = (const float*)d_in[7];
    const float* b1  = (const float*)d_in[8];
    const float* Ws2 = (const float*)d_in[9];
    const float* Wn2 = (const float*)d_in[10];
    const float* b2  = (const float*)d_in[11];
    float* out = (float*)d_out;

    const int NN = in_sizes[0] / NFEAT;   // 50000
    const int E  = in_sizes[1];           // 800000

    char* w = (char*)d_ws;
    ushort* X16  = (ushort*)w; w += align_up((size_t)NN * NFEAT * 2);
    ushort* Ha   = (ushort*)w; w += align_up((size_t)NN * NFEAT * 2);
    ushort* Hb   = (ushort*)w; w += align_up((size_t)NN * NFEAT * 2);
    ushort* Wt0  = (ushort*)w; w += align_up((size_t)128 * 256 * 2);
    ushort* Wt1  = (ushort*)w; w += align_up((size_t)128 * 256 * 2);
    ushort* Wt2  = (ushort*)w; w += align_up((size_t)64 * 256 * 2);
    int* ptrA    = (int*)w;    w += align_up((size_t)(NN + 1) * 4);
    int* deg4    = (int*)w;    w += align_up((size_t)4 * NN * 4);
    int* off1    = (int*)w;    w += align_up((size_t)NN * 4);
    int* off2    = (int*)w;    w += align_up((size_t)NN * 4);
    int* off3    = (int*)w;    w += align_up((size_t)NN * 4);
    int* parts   = (int*)w;    w += align_up(256 * 4);
    int* csr     = (int*)w;    w += align_up((size_t)E * 4);

    // aliased scratch (lifetimes disjoint):
    int*    rnk = (int*)Ha;      // CSR build only, before Ha written
    ushort* G2  = X16;           // layer-2 projected table, after X16 dead

    hipMemsetAsync(deg4, 0, (size_t)4 * NN * 4, stream);

    const int e4b  = (E / 4 + 255) / 256;
    const int n2   = NN * NFEAT / 2;
    const int cvtb = (n2 + 255) / 256;
    const int wb   = (81920 + 255) / 256;
    const int nb   = (NN + 255) / 256;   // 196 <= 256: single-block scan2 ok

    k_prep<<<e4b + cvtb + wb, 256, 0, stream>>>(
        dst, deg4, rnk, E, NN, x, X16, n2,
        Ws0, Wn0, Ws1, Wn1, Ws2, Wn2, Wt0, Wt1, Wt2, e4b, cvtb);
    k_scan1<<<nb, 256, 0, stream>>>(deg4, off1, off2, off3, ptrA, parts, NN);
    k_scan2<<<1, 256, 0, stream>>>(parts, nb);
    k_scan3<<<nb, 256, 0, stream>>>(ptrA, parts, NN, E);
    k_scatter<<<e4b, 256, 0, stream>>>(src, dst, rnk, ptrA, off1, off2, off3, csr, E);

    const int gm = (NN + 127) / 128;

    // layer 0 and 1 (fused agg + GEMM, ReLU, bf16 out)
    k_fused128<<<gm, 256, 0, stream>>>(X16, ptrA, csr, Wt0, b0, Ha, NN);
    k_fused128<<<gm, 256, 0, stream>>>(Ha, ptrA, csr, Wt1, b1, Hb, NN);

    // layer 2: project then fused gather+self-GEMM
    gemm_proj<64, 4><<<gm, 128, 0, stream>>>(Hb, Wt2 + 128, 256, G2, NN);
    k_fused64<<<gm, 128, 0, stream>>>(G2, Hb, ptrA, csr, Wt2, b2, out, NN);
}

// Round 6
// 325.866 us; speedup vs baseline: 1.6204x; 1.6204x over previous
//
#include <hip/hip_runtime.h>
#include <hip/hip_bf16.h>

// GraphSAGE on MI355X — round 6: round-4 structure (separate high-occupancy
// agg + MFMA GEMM) with dispatch-count reduction: k_prep merges degree-count/
// cvt/weight-prep; k_scanB merges scan2+scan3. 12 dispatches total.

#define NFEAT 128

typedef __attribute__((ext_vector_type(8))) short short8;
typedef __attribute__((ext_vector_type(4))) float floatx4;

__device__ __forceinline__ float bf_lo(unsigned u) { return __uint_as_float(u << 16); }
__device__ __forceinline__ float bf_hi(unsigned u) { return __uint_as_float(u & 0xffff0000u); }
__device__ __forceinline__ ushort f2bf(float f) {
    __hip_bfloat16 h = __float2bfloat16(f);
    return *(ushort*)&h;
}
__device__ __forceinline__ unsigned pack2(float a, float b) {
    return (unsigned)f2bf(a) | ((unsigned)f2bf(b) << 16);
}

// ---------------- combined prep: degree count (4-way split) + x->bf16 + weight prep ----------------

__global__ __launch_bounds__(256) void k_prep(
    const int* __restrict__ dst, int* __restrict__ deg4, int* __restrict__ rnk,
    int E, int NN,
    const float* __restrict__ X, ushort* __restrict__ X16, int n2,
    const float* __restrict__ Ws0, const float* __restrict__ Wn0,
    const float* __restrict__ Ws1, const float* __restrict__ Wn1,
    const float* __restrict__ Ws2, const float* __restrict__ Wn2,
    ushort* __restrict__ Wt0, ushort* __restrict__ Wt1, ushort* __restrict__ Wt2,
    int e4b, int cvtb) {
    int b = blockIdx.x, t = threadIdx.x;
    if (b < e4b) {
        int base = (b * 256 + t) * 4;
        if (base + 4 <= E) {
            int4 d4 = *(const int4*)(dst + base);
            int4 r4;
            r4.x = atomicAdd(&deg4[0 * NN + d4.x], 1);
            r4.y = atomicAdd(&deg4[1 * NN + d4.y], 1);
            r4.z = atomicAdd(&deg4[2 * NN + d4.z], 1);
            r4.w = atomicAdd(&deg4[3 * NN + d4.w], 1);
            *(int4*)(rnk + base) = r4;
        } else {
            for (int e = base; e < E; ++e)
                rnk[e] = atomicAdd(&deg4[(e & 3) * NN + dst[e]], 1);
        }
    } else if (b < e4b + cvtb) {
        int i = (b - e4b) * 256 + t;
        if (i < n2) {
            float2 v = ((const float2*)X)[i];
            ((unsigned*)X16)[i] = pack2(v.x, v.y);
        }
    } else {
        int idx = (b - e4b - cvtb) * 256 + t;
        if (idx < 32768) {
            int n = idx >> 8, k = idx & 255;
            Wt0[idx] = f2bf(k < 128 ? Ws0[k * 128 + n] : Wn0[(k - 128) * 128 + n]);
        } else if (idx < 65536) {
            int l = idx - 32768, n = l >> 8, k = l & 255;
            Wt1[l] = f2bf(k < 128 ? Ws1[k * 128 + n] : Wn1[(k - 128) * 128 + n]);
        } else if (idx < 81920) {
            int l = idx - 65536, n = l >> 8, k = l & 255;
            Wt2[l] = f2bf(k < 128 ? Ws2[k * 64 + n] : Wn2[(k - 128) * 64 + n]);
        }
    }
}

// ---------------- scans ----------------

// block-local exclusive scan of total degree; also emits quarter offsets
__global__ void k_scan1(const int* __restrict__ deg4, int* __restrict__ off1,
                        int* __restrict__ off2, int* __restrict__ off3,
                        int* __restrict__ ptrA, int* __restrict__ partials, int NN) {
    __shared__ int sh[256];
    int t = threadIdx.x;
    int i = blockIdx.x * 256 + t;
    int d0 = 0, d1 = 0, d2 = 0, d3 = 0;
    if (i < NN) {
        d0 = deg4[i]; d1 = deg4[NN + i]; d2 = deg4[2 * NN + i]; d3 = deg4[3 * NN + i];
        off1[i] = d0; off2[i] = d0 + d1; off3[i] = d0 + d1 + d2;
    }
    int v = d0 + d1 + d2 + d3;
    sh[t] = v;
    __syncthreads();
#pragma unroll
    for (int off = 1; off < 256; off <<= 1) {
        int x = (t >= off) ? sh[t - off] : 0;
        __syncthreads();
        sh[t] += x;
        __syncthreads();
    }
    if (i < NN) ptrA[i] = sh[t] - v;
    if (t == 255) partials[blockIdx.x] = sh[255];
}

// fused scan2+scan3: each block recomputes the partial-prefix it needs
__global__ void k_scanB(int* __restrict__ ptrA, const int* __restrict__ partials,
                        int NN, int E, int nb) {
    __shared__ int sh[256];
    int t = threadIdx.x, bid = blockIdx.x;
    int v = (t < bid && t < nb) ? partials[t] : 0;   // sum over blocks < bid
    sh[t] = v;
    __syncthreads();
#pragma unroll
    for (int off = 128; off > 0; off >>= 1) {
        if (t < off) sh[t] += sh[t + off];
        __syncthreads();
    }
    int pre = sh[0];
    int i = bid * 256 + t;
    if (i < NN) ptrA[i] += pre;
    if (bid == 0 && t == 0) ptrA[NN] = E;
}

__global__ __launch_bounds__(256) void k_scatter(const int* __restrict__ src,
                                                 const int* __restrict__ dst,
                                                 const int* __restrict__ rnk,
                                                 const int* __restrict__ ptrA,
                                                 const int* __restrict__ off1,
                                                 const int* __restrict__ off2,
                                                 const int* __restrict__ off3,
                                                 int* __restrict__ csr, int E) {
    int base = (blockIdx.x * 256 + threadIdx.x) * 4;
    if (base + 4 <= E) {
        int4 d4 = *(const int4*)(dst + base);
        int4 r4 = *(const int4*)(rnk + base);
        int4 s4 = *(const int4*)(src + base);
        csr[ptrA[d4.x] + r4.x] = s4.x;
        csr[ptrA[d4.y] + off1[d4.y] + r4.y] = s4.y;
        csr[ptrA[d4.z] + off2[d4.z] + r4.z] = s4.z;
        csr[ptrA[d4.w] + off3[d4.w] + r4.w] = s4.w;
    } else {
        for (int e = base; e < E; ++e) {
            int d = dst[e], q = e & 3;
            int off = (q == 0) ? 0 : ((q == 1) ? off1[d] : ((q == 2) ? off2[d] : off3[d]));
            csr[ptrA[d] + off + rnk[e]] = src[e];
        }
    }
}

// ---------------- mean aggregation: one wave per node (high occupancy) ----------------

template <int FEAT, bool OUT_BF16>
__global__ __launch_bounds__(256) void k_agg_t(const ushort* __restrict__ H,
                                               const int* __restrict__ ptrA,
                                               const int* __restrict__ csr,
                                               void* __restrict__ outp, int NN) {
    constexpr int LPR = FEAT / 8;   // lanes per row (16B chunks of 8 bf16)
    constexpr int EPG = 64 / LPR;   // edges per wave-iteration
    int node = (blockIdx.x * 256 + threadIdx.x) >> 6;
    if (node >= NN) return;
    int lane = threadIdx.x & 63;
    int sub = lane / LPR, fl = lane % LPR;
    int beg = ptrA[node], end = ptrA[node + 1];
    float acc[8] = {};
    int e = beg + sub;
    for (; e + EPG < end; e += 2 * EPG) {   // 2 independent row-gathers in flight
        int r0 = csr[e], r1 = csr[e + EPG];
        uint4 v0 = *(const uint4*)(H + (size_t)r0 * FEAT + fl * 8);
        uint4 v1 = *(const uint4*)(H + (size_t)r1 * FEAT + fl * 8);
        acc[0] += bf_lo(v0.x) + bf_lo(v1.x); acc[1] += bf_hi(v0.x) + bf_hi(v1.x);
        acc[2] += bf_lo(v0.y) + bf_lo(v1.y); acc[3] += bf_hi(v0.y) + bf_hi(v1.y);
        acc[4] += bf_lo(v0.z) + bf_lo(v1.z); acc[5] += bf_hi(v0.z) + bf_hi(v1.z);
        acc[6] += bf_lo(v0.w) + bf_lo(v1.w); acc[7] += bf_hi(v0.w) + bf_hi(v1.w);
    }
    for (; e < end; e += EPG) {
        int r = csr[e];
        uint4 v = *(const uint4*)(H + (size_t)r * FEAT + fl * 8);
        acc[0] += bf_lo(v.x); acc[1] += bf_hi(v.x);
        acc[2] += bf_lo(v.y); acc[3] += bf_hi(v.y);
        acc[4] += bf_lo(v.z); acc[5] += bf_hi(v.z);
        acc[6] += bf_lo(v.w); acc[7] += bf_hi(v.w);
    }
#pragma unroll
    for (int off = LPR; off < 64; off <<= 1)
#pragma unroll
        for (int i = 0; i < 8; ++i) acc[i] += __shfl_xor(acc[i], off, 64);
    if (sub == 0) {
        int d = end - beg;
        float inv = (d > 0) ? 1.0f / (float)d : 0.0f;
        if constexpr (OUT_BF16) {
            unsigned u[4];
#pragma unroll
            for (int i = 0; i < 4; ++i)
                u[i] = pack2(acc[2 * i] * inv, acc[2 * i + 1] * inv);
            *(uint4*)((ushort*)outp + (size_t)node * FEAT + fl * 8) =
                make_uint4(u[0], u[1], u[2], u[3]);
        } else {
            float* O = (float*)outp;
            size_t b = (size_t)node * FEAT + fl * 8;
#pragma unroll
            for (int i = 0; i < 8; ++i) O[b + i] = acc[i] * inv;
        }
    }
}

// ---------------- MFMA GEMM ----------------
// C = A @ Wt^T (+bias) (+addin) (+ReLU). SPLIT: A = [Hs | Ag] along K.
// BM=128, BK=32. Waves 2(m) x BN/64(n), wave tile 64x64 of 16x16x32 MFMA.
// LDS rows padded to 40 ushorts (80B) -> conflict-free ds_read_b128.

template <int BN, int NKB, bool SPLIT, bool OUT_BF16>
__global__ __launch_bounds__(64 * 2 * (BN / 64)) void gemm_mfma(
    const ushort* __restrict__ Hs, const ushort* __restrict__ Ag,
    const ushort* __restrict__ Wt, int ldw, const float* __restrict__ bias,
    const float* __restrict__ addin, void* __restrict__ Cout, int M, int relu) {
    constexpr int WN = BN / 64;
    constexpr int NTHR = 64 * 2 * WN;
    constexpr int LDA = 40;
    __shared__ ushort Asl[128 * LDA];
    __shared__ ushort Bsl[BN * LDA];

    int t = threadIdx.x;
    int lane = t & 63;
    int wid = t >> 6;
    int wm = wid & 1, wn = wid >> 1;
    int l15 = lane & 15, quad = lane >> 4;
    int m0 = blockIdx.x * 128;

    floatx4 acc[4][4] = {};

    for (int kb = 0; kb < NKB; ++kb) {
        const ushort* Asrc;
        int kOff;
        if constexpr (SPLIT) {
            Asrc = (kb < NKB / 2) ? Hs : Ag;
            kOff = (kb & (NKB / 2 - 1)) * 32;
        } else {
            Asrc = Hs;
            kOff = kb * 32;
        }
        __syncthreads();
#pragma unroll
        for (int id = t; id < 128 * 4; id += NTHR) {
            int r = id >> 2, p = id & 3;
            uint4 v = make_uint4(0, 0, 0, 0);
            if (m0 + r < M) v = *(const uint4*)(Asrc + (size_t)(m0 + r) * NFEAT + kOff + p * 8);
            *(uint4*)(&Asl[r * LDA + p * 8]) = v;
        }
#pragma unroll
        for (int id = t; id < BN * 4; id += NTHR) {
            int r = id >> 2, p = id & 3;
            uint4 v = *(const uint4*)(Wt + (size_t)r * ldw + kb * 32 + p * 8);
            *(uint4*)(&Bsl[r * LDA + p * 8]) = v;
        }
        __syncthreads();

        short8 a[4], b[4];
#pragma unroll
        for (int mt = 0; mt < 4; ++mt)
            a[mt] = *(const short8*)(&Asl[(wm * 64 + mt * 16 + l15) * LDA + quad * 8]);
#pragma unroll
        for (int nt = 0; nt < 4; ++nt)
            b[nt] = *(const short8*)(&Bsl[(wn * 64 + nt * 16 + l15) * LDA + quad * 8]);
#pragma unroll
        for (int mt = 0; mt < 4; ++mt)
#pragma unroll
            for (int nt = 0; nt < 4; ++nt)
                acc[mt][nt] = __builtin_amdgcn_mfma_f32_16x16x32_bf16(a[mt], b[nt], acc[mt][nt], 0, 0, 0);
    }

#pragma unroll
    for (int mt = 0; mt < 4; ++mt) {
        int mbase = m0 + wm * 64 + mt * 16 + quad * 4;
#pragma unroll
        for (int nt = 0; nt < 4; ++nt) {
            int col = wn * 64 + nt * 16 + l15;
            float bv = bias ? bias[col] : 0.0f;
#pragma unroll
            for (int r = 0; r < 4; ++r) {
                int m = mbase + r;
                if (m < M) {
                    float v = acc[mt][nt][r] + bv;
                    if (addin) v += addin[(size_t)m * BN + col];
                    if (relu) v = fmaxf(v, 0.f);
                    if constexpr (OUT_BF16) {
                        ((unsigned short*)Cout)[(size_t)m * BN + col] = f2bf(v);
                    } else {
                        ((float*)Cout)[(size_t)m * BN + col] = v;
                    }
                }
            }
        }
    }
}

// ---------------- launch ----------------

static inline size_t align_up(size_t x) { return (x + 255) & ~(size_t)255; }

extern "C" void kernel_launch(void* const* d_in, const int* in_sizes, int n_in,
                              void* d_out, int out_size, void* d_ws, size_t ws_size,
                              hipStream_t stream) {
    const float* x   = (const float*)d_in[0];
    const int*   src = (const int*)d_in[1];
    const int*   dst = (const int*)d_in[2];
    const float* Ws0 = (const float*)d_in[3];
    const float* Wn0 = (const float*)d_in[4];
    const float* b0  = (const float*)d_in[5];
    const float* Ws1 = (const float*)d_in[6];
    const float* Wn1 = (const float*)d_in[7];
    const float* b1  = (const float*)d_in[8];
    const float* Ws2 = (const float*)d_in[9];
    const float* Wn2 = (const float*)d_in[10];
    const float* b2  = (const float*)d_in[11];
    float* out = (float*)d_out;

    const int NN = in_sizes[0] / NFEAT;   // 50000
    const int E  = in_sizes[1];           // 800000

    char* w = (char*)d_ws;
    ushort* X16  = (ushort*)w; w += align_up((size_t)NN * NFEAT * 2);
    ushort* Ha   = (ushort*)w; w += align_up((size_t)NN * NFEAT * 2);
    ushort* Hb   = (ushort*)w; w += align_up((size_t)NN * NFEAT * 2);
    ushort* AGG  = (ushort*)w; w += align_up((size_t)NN * NFEAT * 2);
    ushort* Wt0  = (ushort*)w; w += align_up((size_t)128 * 256 * 2);
    ushort* Wt1  = (ushort*)w; w += align_up((size_t)128 * 256 * 2);
    ushort* Wt2  = (ushort*)w; w += align_up((size_t)64 * 256 * 2);
    int* ptrA    = (int*)w;    w += align_up((size_t)(NN + 1) * 4);
    int* deg4    = (int*)w;    w += align_up((size_t)4 * NN * 4);
    int* off1    = (int*)w;    w += align_up((size_t)NN * 4);
    int* off2    = (int*)w;    w += align_up((size_t)NN * 4);
    int* off3    = (int*)w;    w += align_up((size_t)NN * 4);
    int* parts   = (int*)w;    w += align_up(256 * 4);
    int* csr     = (int*)w;    w += align_up((size_t)E * 4);

    // aliased scratch (lifetimes disjoint):
    int*    rnk = (int*)Ha;      // CSR build only, before Ha written
    ushort* G2  = X16;           // layer-2 projected table, after X16 dead
    float*  A2  = (float*)AGG;   // layer-2 fp32 aggregate, after AGG dead

    hipMemsetAsync(deg4, 0, (size_t)4 * NN * 4, stream);

    const int e4b  = (E / 4 + 255) / 256;
    const int n2   = NN * NFEAT / 2;
    const int cvtb = (n2 + 255) / 256;
    const int wb   = (81920 + 255) / 256;
    const int nb   = (NN + 255) / 256;   // 196 <= 256: fits one scanB pass

    k_prep<<<e4b + cvtb + wb, 256, 0, stream>>>(
        dst, deg4, rnk, E, NN, x, X16, n2,
        Ws0, Wn0, Ws1, Wn1, Ws2, Wn2, Wt0, Wt1, Wt2, e4b, cvtb);
    k_scan1<<<nb, 256, 0, stream>>>(deg4, off1, off2, off3, ptrA, parts, NN);
    k_scanB<<<nb, 256, 0, stream>>>(ptrA, parts, NN, E, nb);
    k_scatter<<<e4b, 256, 0, stream>>>(src, dst, rnk, ptrA, off1, off2, off3, csr, E);

    const int ab = (NN * 64 + 255) / 256;
    const int gm = (NN + 127) / 128;

    // layer 0: X16 -> Ha (ReLU)
    k_agg_t<128, true><<<ab, 256, 0, stream>>>(X16, ptrA, csr, AGG, NN);
    gemm_mfma<128, 8, true, true><<<gm, 256, 0, stream>>>(X16, AGG, Wt0, 256, b0, nullptr, Ha, NN, 1);

    // layer 1: Ha -> Hb (ReLU)
    k_agg_t<128, true><<<ab, 256, 0, stream>>>(Ha, ptrA, csr, AGG, NN);
    gemm_mfma<128, 8, true, true><<<gm, 256, 0, stream>>>(Ha, AGG, Wt1, 256, b1, nullptr, Hb, NN, 1);

    // layer 2: agg(Hb)@Wn2 == agg(Hb@Wn2) -> 64-wide gather table
    gemm_mfma<64, 4, false, true><<<gm, 128, 0, stream>>>(Hb, nullptr, Wt2 + 128, 256, nullptr, nullptr, G2, NN, 0);
    k_agg_t<64, false><<<ab, 256, 0, stream>>>(G2, ptrA, csr, A2, NN);
    gemm_mfma<64, 4, false, false><<<gm, 128, 0, stream>>>(Hb, nullptr, Wt2, 256, b2, A2, out, NN, 0);
}

// Round 7
// 322.098 us; speedup vs baseline: 1.6394x; 1.0117x over previous
//
#include <hip/hip_runtime.h>
#include <hip/hip_bf16.h>

// GraphSAGE on MI355X — round 7.
// vs round 6: (1) degree counters padded to one per 64B line (test per-line
// atomic serialization theory), (2) scanB precomputes qb1..3 = ptrA+offq so
// scatter does 1 random read/edge, (3) agg gather 4x/2x/1x unroll ladder.

#define NFEAT 128

typedef __attribute__((ext_vector_type(8))) short short8;
typedef __attribute__((ext_vector_type(4))) float floatx4;

__device__ __forceinline__ float bf_lo(unsigned u) { return __uint_as_float(u << 16); }
__device__ __forceinline__ float bf_hi(unsigned u) { return __uint_as_float(u & 0xffff0000u); }
__device__ __forceinline__ ushort f2bf(float f) {
    __hip_bfloat16 h = __float2bfloat16(f);
    return *(ushort*)&h;
}
__device__ __forceinline__ unsigned pack2(float a, float b) {
    return (unsigned)f2bf(a) | ((unsigned)f2bf(b) << 16);
}

// ---------------- combined prep: degree count (line-padded, 4-way split) + x->bf16 + weight prep ----
// counter for (node, quarter q) lives at degP[(node*4+q)*16] — one per 64B line.

__global__ __launch_bounds__(256) void k_prep(
    const int* __restrict__ dst, int* __restrict__ degP, int* __restrict__ rnk,
    int E, int NN,
    const float* __restrict__ X, ushort* __restrict__ X16, int n2,
    const float* __restrict__ Ws0, const float* __restrict__ Wn0,
    const float* __restrict__ Ws1, const float* __restrict__ Wn1,
    const float* __restrict__ Ws2, const float* __restrict__ Wn2,
    ushort* __restrict__ Wt0, ushort* __restrict__ Wt1, ushort* __restrict__ Wt2,
    int e4b, int cvtb) {
    int b = blockIdx.x, t = threadIdx.x;
    if (b < e4b) {
        int base = (b * 256 + t) * 4;
        if (base + 4 <= E) {
            int4 d4 = *(const int4*)(dst + base);
            int4 r4;
            r4.x = atomicAdd(&degP[(d4.x * 4 + 0) << 4], 1);
            r4.y = atomicAdd(&degP[(d4.y * 4 + 1) << 4], 1);
            r4.z = atomicAdd(&degP[(d4.z * 4 + 2) << 4], 1);
            r4.w = atomicAdd(&degP[(d4.w * 4 + 3) << 4], 1);
            *(int4*)(rnk + base) = r4;
        } else {
            for (int e = base; e < E; ++e)
                rnk[e] = atomicAdd(&degP[(dst[e] * 4 + (e & 3)) << 4], 1);
        }
    } else if (b < e4b + cvtb) {
        int i = (b - e4b) * 256 + t;
        if (i < n2) {
            float2 v = ((const float2*)X)[i];
            ((unsigned*)X16)[i] = pack2(v.x, v.y);
        }
    } else {
        int idx = (b - e4b - cvtb) * 256 + t;
        if (idx < 32768) {
            int n = idx >> 8, k = idx & 255;
            Wt0[idx] = f2bf(k < 128 ? Ws0[k * 128 + n] : Wn0[(k - 128) * 128 + n]);
        } else if (idx < 65536) {
            int l = idx - 32768, n = l >> 8, k = l & 255;
            Wt1[l] = f2bf(k < 128 ? Ws1[k * 128 + n] : Wn1[(k - 128) * 128 + n]);
        } else if (idx < 81920) {
            int l = idx - 65536, n = l >> 8, k = l & 255;
            Wt2[l] = f2bf(k < 128 ? Ws2[k * 64 + n] : Wn2[(k - 128) * 64 + n]);
        }
    }
}

// ---------------- scans ----------------

__global__ void k_scan1(const int* __restrict__ degP, int* __restrict__ off1,
                        int* __restrict__ off2, int* __restrict__ off3,
                        int* __restrict__ ptrA, int* __restrict__ partials, int NN) {
    __shared__ int sh[256];
    int t = threadIdx.x;
    int i = blockIdx.x * 256 + t;
    int d0 = 0, d1 = 0, d2 = 0, d3 = 0;
    if (i < NN) {
        d0 = degP[(i * 4 + 0) << 4];
        d1 = degP[(i * 4 + 1) << 4];
        d2 = degP[(i * 4 + 2) << 4];
        d3 = degP[(i * 4 + 3) << 4];
        off1[i] = d0; off2[i] = d0 + d1; off3[i] = d0 + d1 + d2;
    }
    int v = d0 + d1 + d2 + d3;
    sh[t] = v;
    __syncthreads();
#pragma unroll
    for (int off = 1; off < 256; off <<= 1) {
        int x = (t >= off) ? sh[t - off] : 0;
        __syncthreads();
        sh[t] += x;
        __syncthreads();
    }
    if (i < NN) ptrA[i] = sh[t] - v;
    if (t == 255) partials[blockIdx.x] = sh[255];
}

// fused scan2+scan3 + qbase precompute (qbN = final ptrA + quarter offset)
__global__ void k_scanB(int* __restrict__ ptrA, const int* __restrict__ partials,
                        const int* __restrict__ off1, const int* __restrict__ off2,
                        const int* __restrict__ off3, int* __restrict__ qb1,
                        int* __restrict__ qb2, int* __restrict__ qb3,
                        int NN, int E, int nb) {
    __shared__ int sh[256];
    int t = threadIdx.x, bid = blockIdx.x;
    int v = (t < bid && t < nb) ? partials[t] : 0;
    sh[t] = v;
    __syncthreads();
#pragma unroll
    for (int off = 128; off > 0; off >>= 1) {
        if (t < off) sh[t] += sh[t + off];
        __syncthreads();
    }
    int pre = sh[0];
    int i = bid * 256 + t;
    if (i < NN) {
        int p = ptrA[i] + pre;
        ptrA[i] = p;
        qb1[i] = p + off1[i];
        qb2[i] = p + off2[i];
        qb3[i] = p + off3[i];
    }
    if (bid == 0 && t == 0) ptrA[NN] = E;
}

__global__ __launch_bounds__(256) void k_scatter(const int* __restrict__ src,
                                                 const int* __restrict__ dst,
                                                 const int* __restrict__ rnk,
                                                 const int* __restrict__ ptrA,
                                                 const int* __restrict__ qb1,
                                                 const int* __restrict__ qb2,
                                                 const int* __restrict__ qb3,
                                                 int* __restrict__ csr, int E) {
    int base = (blockIdx.x * 256 + threadIdx.x) * 4;
    if (base + 4 <= E) {
        int4 d4 = *(const int4*)(dst + base);
        int4 r4 = *(const int4*)(rnk + base);
        int4 s4 = *(const int4*)(src + base);
        csr[ptrA[d4.x] + r4.x] = s4.x;
        csr[qb1[d4.y] + r4.y] = s4.y;
        csr[qb2[d4.z] + r4.z] = s4.z;
        csr[qb3[d4.w] + r4.w] = s4.w;
    } else {
        for (int e = base; e < E; ++e) {
            int d = dst[e], q = e & 3;
            const int* qb = (q == 0) ? ptrA : ((q == 1) ? qb1 : ((q == 2) ? qb2 : qb3));
            csr[qb[d] + rnk[e]] = src[e];
        }
    }
}

// ---------------- mean aggregation: one wave per node, 4x/2x/1x gather ladder ----------------

template <int FEAT, bool OUT_BF16>
__global__ __launch_bounds__(256) void k_agg_t(const ushort* __restrict__ H,
                                               const int* __restrict__ ptrA,
                                               const int* __restrict__ csr,
                                               void* __restrict__ outp, int NN) {
    constexpr int LPR = FEAT / 8;   // lanes per row (16B chunks of 8 bf16)
    constexpr int EPG = 64 / LPR;   // edges per wave-iteration
    int node = (blockIdx.x * 256 + threadIdx.x) >> 6;
    if (node >= NN) return;
    int lane = threadIdx.x & 63;
    int sub = lane / LPR, fl = lane % LPR;
    int beg = ptrA[node], end = ptrA[node + 1];
    float acc[8] = {};
    int e = beg + sub;
    for (; e + 3 * EPG < end; e += 4 * EPG) {   // 4 rows in flight
        int r0 = csr[e], r1 = csr[e + EPG], r2 = csr[e + 2 * EPG], r3 = csr[e + 3 * EPG];
        uint4 v0 = *(const uint4*)(H + (size_t)r0 * FEAT + fl * 8);
        uint4 v1 = *(const uint4*)(H + (size_t)r1 * FEAT + fl * 8);
        uint4 v2 = *(const uint4*)(H + (size_t)r2 * FEAT + fl * 8);
        uint4 v3 = *(const uint4*)(H + (size_t)r3 * FEAT + fl * 8);
        acc[0] += bf_lo(v0.x) + bf_lo(v1.x) + bf_lo(v2.x) + bf_lo(v3.x);
        acc[1] += bf_hi(v0.x) + bf_hi(v1.x) + bf_hi(v2.x) + bf_hi(v3.x);
        acc[2] += bf_lo(v0.y) + bf_lo(v1.y) + bf_lo(v2.y) + bf_lo(v3.y);
        acc[3] += bf_hi(v0.y) + bf_hi(v1.y) + bf_hi(v2.y) + bf_hi(v3.y);
        acc[4] += bf_lo(v0.z) + bf_lo(v1.z) + bf_lo(v2.z) + bf_lo(v3.z);
        acc[5] += bf_hi(v0.z) + bf_hi(v1.z) + bf_hi(v2.z) + bf_hi(v3.z);
        acc[6] += bf_lo(v0.w) + bf_lo(v1.w) + bf_lo(v2.w) + bf_lo(v3.w);
        acc[7] += bf_hi(v0.w) + bf_hi(v1.w) + bf_hi(v2.w) + bf_hi(v3.w);
    }
    for (; e + EPG < end; e += 2 * EPG) {       // 2 rows in flight
        int r0 = csr[e], r1 = csr[e + EPG];
        uint4 v0 = *(const uint4*)(H + (size_t)r0 * FEAT + fl * 8);
        uint4 v1 = *(const uint4*)(H + (size_t)r1 * FEAT + fl * 8);
        acc[0] += bf_lo(v0.x) + bf_lo(v1.x); acc[1] += bf_hi(v0.x) + bf_hi(v1.x);
        acc[2] += bf_lo(v0.y) + bf_lo(v1.y); acc[3] += bf_hi(v0.y) + bf_hi(v1.y);
        acc[4] += bf_lo(v0.z) + bf_lo(v1.z); acc[5] += bf_hi(v0.z) + bf_hi(v1.z);
        acc[6] += bf_lo(v0.w) + bf_lo(v1.w); acc[7] += bf_hi(v0.w) + bf_hi(v1.w);
    }
    for (; e < end; e += EPG) {
        int r = csr[e];
        uint4 v = *(const uint4*)(H + (size_t)r * FEAT + fl * 8);
        acc[0] += bf_lo(v.x); acc[1] += bf_hi(v.x);
        acc[2] += bf_lo(v.y); acc[3] += bf_hi(v.y);
        acc[4] += bf_lo(v.z); acc[5] += bf_hi(v.z);
        acc[6] += bf_lo(v.w); acc[7] += bf_hi(v.w);
    }
#pragma unroll
    for (int off = LPR; off < 64; off <<= 1)
#pragma unroll
        for (int i = 0; i < 8; ++i) acc[i] += __shfl_xor(acc[i], off, 64);
    if (sub == 0) {
        int d = end - beg;
        float inv = (d > 0) ? 1.0f / (float)d : 0.0f;
        if constexpr (OUT_BF16) {
            unsigned u[4];
#pragma unroll
            for (int i = 0; i < 4; ++i)
                u[i] = pack2(acc[2 * i] * inv, acc[2 * i + 1] * inv);
            *(uint4*)((ushort*)outp + (size_t)node * FEAT + fl * 8) =
                make_uint4(u[0], u[1], u[2], u[3]);
        } else {
            float* O = (float*)outp;
            size_t b = (size_t)node * FEAT + fl * 8;
#pragma unroll
            for (int i = 0; i < 8; ++i) O[b + i] = acc[i] * inv;
        }
    }
}

// ---------------- MFMA GEMM ----------------
// C = A @ Wt^T (+bias) (+addin) (+ReLU). SPLIT: A = [Hs | Ag] along K.
// BM=128, BK=32. Waves 2(m) x BN/64(n), wave tile 64x64 of 16x16x32 MFMA.
// LDS rows padded to 40 ushorts (80B) -> conflict-free ds_read_b128.

template <int BN, int NKB, bool SPLIT, bool OUT_BF16>
__global__ __launch_bounds__(64 * 2 * (BN / 64)) void gemm_mfma(
    const ushort* __restrict__ Hs, const ushort* __restrict__ Ag,
    const ushort* __restrict__ Wt, int ldw, const float* __restrict__ bias,
    const float* __restrict__ addin, void* __restrict__ Cout, int M, int relu) {
    constexpr int WN = BN / 64;
    constexpr int NTHR = 64 * 2 * WN;
    constexpr int LDA = 40;
    __shared__ ushort Asl[128 * LDA];
    __shared__ ushort Bsl[BN * LDA];

    int t = threadIdx.x;
    int lane = t & 63;
    int wid = t >> 6;
    int wm = wid & 1, wn = wid >> 1;
    int l15 = lane & 15, quad = lane >> 4;
    int m0 = blockIdx.x * 128;

    floatx4 acc[4][4] = {};

    for (int kb = 0; kb < NKB; ++kb) {
        const ushort* Asrc;
        int kOff;
        if constexpr (SPLIT) {
            Asrc = (kb < NKB / 2) ? Hs : Ag;
            kOff = (kb & (NKB / 2 - 1)) * 32;
        } else {
            Asrc = Hs;
            kOff = kb * 32;
        }
        __syncthreads();
#pragma unroll
        for (int id = t; id < 128 * 4; id += NTHR) {
            int r = id >> 2, p = id & 3;
            uint4 v = make_uint4(0, 0, 0, 0);
            if (m0 + r < M) v = *(const uint4*)(Asrc + (size_t)(m0 + r) * NFEAT + kOff + p * 8);
            *(uint4*)(&Asl[r * LDA + p * 8]) = v;
        }
#pragma unroll
        for (int id = t; id < BN * 4; id += NTHR) {
            int r = id >> 2, p = id & 3;
            uint4 v = *(const uint4*)(Wt + (size_t)r * ldw + kb * 32 + p * 8);
            *(uint4*)(&Bsl[r * LDA + p * 8]) = v;
        }
        __syncthreads();

        short8 a[4], b[4];
#pragma unroll
        for (int mt = 0; mt < 4; ++mt)
            a[mt] = *(const short8*)(&Asl[(wm * 64 + mt * 16 + l15) * LDA + quad * 8]);
#pragma unroll
        for (int nt = 0; nt < 4; ++nt)
            b[nt] = *(const short8*)(&Bsl[(wn * 64 + nt * 16 + l15) * LDA + quad * 8]);
#pragma unroll
        for (int mt = 0; mt < 4; ++mt)
#pragma unroll
            for (int nt = 0; nt < 4; ++nt)
                acc[mt][nt] = __builtin_amdgcn_mfma_f32_16x16x32_bf16(a[mt], b[nt], acc[mt][nt], 0, 0, 0);
    }

#pragma unroll
    for (int mt = 0; mt < 4; ++mt) {
        int mbase = m0 + wm * 64 + mt * 16 + quad * 4;
#pragma unroll
        for (int nt = 0; nt < 4; ++nt) {
            int col = wn * 64 + nt * 16 + l15;
            float bv = bias ? bias[col] : 0.0f;
#pragma unroll
            for (int r = 0; r < 4; ++r) {
                int m = mbase + r;
                if (m < M) {
                    float v = acc[mt][nt][r] + bv;
                    if (addin) v += addin[(size_t)m * BN + col];
                    if (relu) v = fmaxf(v, 0.f);
                    if constexpr (OUT_BF16) {
                        ((unsigned short*)Cout)[(size_t)m * BN + col] = f2bf(v);
                    } else {
                        ((float*)Cout)[(size_t)m * BN + col] = v;
                    }
                }
            }
        }
    }
}

// ---------------- launch ----------------

static inline size_t align_up(size_t x) { return (x + 255) & ~(size_t)255; }

extern "C" void kernel_launch(void* const* d_in, const int* in_sizes, int n_in,
                              void* d_out, int out_size, void* d_ws, size_t ws_size,
                              hipStream_t stream) {
    const float* x   = (const float*)d_in[0];
    const int*   src = (const int*)d_in[1];
    const int*   dst = (const int*)d_in[2];
    const float* Ws0 = (const float*)d_in[3];
    const float* Wn0 = (const float*)d_in[4];
    const float* b0  = (const float*)d_in[5];
    const float* Ws1 = (const float*)d_in[6];
    const float* Wn1 = (const float*)d_in[7];
    const float* b1  = (const float*)d_in[8];
    const float* Ws2 = (const float*)d_in[9];
    const float* Wn2 = (const float*)d_in[10];
    const float* b2  = (const float*)d_in[11];
    float* out = (float*)d_out;

    const int NN = in_sizes[0] / NFEAT;   // 50000
    const int E  = in_sizes[1];           // 800000

    char* w = (char*)d_ws;
    ushort* X16  = (ushort*)w; w += align_up((size_t)NN * NFEAT * 2);
    ushort* Ha   = (ushort*)w; w += align_up((size_t)NN * NFEAT * 2);
    ushort* Hb   = (ushort*)w; w += align_up((size_t)NN * NFEAT * 2);
    ushort* AGG  = (ushort*)w; w += align_up((size_t)NN * NFEAT * 2);
    ushort* Wt0  = (ushort*)w; w += align_up((size_t)128 * 256 * 2);
    ushort* Wt1  = (ushort*)w; w += align_up((size_t)128 * 256 * 2);
    ushort* Wt2  = (ushort*)w; w += align_up((size_t)64 * 256 * 2);
    int* ptrA    = (int*)w;    w += align_up((size_t)(NN + 1) * 4);
    int* degP    = (int*)w;    w += align_up((size_t)NN * 256);        // 4 ctr/node, 64B apart
    int* off1    = (int*)w;    w += align_up((size_t)NN * 4);
    int* off2    = (int*)w;    w += align_up((size_t)NN * 4);
    int* off3    = (int*)w;    w += align_up((size_t)NN * 4);
    int* qb1     = (int*)w;    w += align_up((size_t)NN * 4);
    int* qb2     = (int*)w;    w += align_up((size_t)NN * 4);
    int* qb3     = (int*)w;    w += align_up((size_t)NN * 4);
    int* parts   = (int*)w;    w += align_up(256 * 4);
    int* csr     = (int*)w;    w += align_up((size_t)E * 4);

    // aliased scratch (lifetimes disjoint):
    int*    rnk = (int*)Ha;      // CSR build only, before Ha written
    ushort* G2  = X16;           // layer-2 projected table, after X16 dead
    float*  A2  = (float*)AGG;   // layer-2 fp32 aggregate, after AGG dead

    hipMemsetAsync(degP, 0, (size_t)NN * 256, stream);

    const int e4b  = (E / 4 + 255) / 256;
    const int n2   = NN * NFEAT / 2;
    const int cvtb = (n2 + 255) / 256;
    const int wb   = (81920 + 255) / 256;
    const int nb   = (NN + 255) / 256;   // 196 <= 256: fits one scanB pass

    k_prep<<<e4b + cvtb + wb, 256, 0, stream>>>(
        dst, degP, rnk, E, NN, x, X16, n2,
        Ws0, Wn0, Ws1, Wn1, Ws2, Wn2, Wt0, Wt1, Wt2, e4b, cvtb);
    k_scan1<<<nb, 256, 0, stream>>>(degP, off1, off2, off3, ptrA, parts, NN);
    k_scanB<<<nb, 256, 0, stream>>>(ptrA, parts, off1, off2, off3, qb1, qb2, qb3, NN, E, nb);
    k_scatter<<<e4b, 256, 0, stream>>>(src, dst, rnk, ptrA, qb1, qb2, qb3, csr, E);

    const int ab = (NN * 64 + 255) / 256;
    const int gm = (NN + 127) / 128;

    // layer 0: X16 -> Ha (ReLU)
    k_agg_t<128, true><<<ab, 256, 0, stream>>>(X16, ptrA, csr, AGG, NN);
    gemm_mfma<128, 8, true, true><<<gm, 256, 0, stream>>>(X16, AGG, Wt0, 256, b0, nullptr, Ha, NN, 1);

    // layer 1: Ha -> Hb (ReLU)
    k_agg_t<128, true><<<ab, 256, 0, stream>>>(Ha, ptrA, csr, AGG, NN);
    gemm_mfma<128, 8, true, true><<<gm, 256, 0, stream>>>(Ha, AGG, Wt1, 256, b1, nullptr, Hb, NN, 1);

    // layer 2: agg(Hb)@Wn2 == agg(Hb@Wn2) -> 64-wide gather table
    gemm_mfma<64, 4, false, true><<<gm, 128, 0, stream>>>(Hb, nullptr, Wt2 + 128, 256, nullptr, nullptr, G2, NN, 0);
    k_agg_t<64, false><<<ab, 256, 0, stream>>>(G2, ptrA, csr, A2, NN);
    gemm_mfma<64, 4, false, false><<<gm, 128, 0, stream>>>(Hb, nullptr, Wt2, 256, b2, A2, out, NN, 0);
}

// Round 8
// 314.711 us; speedup vs baseline: 1.6779x; 1.0235x over previous
//
#include <hip/hip_runtime.h>
#include <hip/hip_bf16.h>

// GraphSAGE on MI355X — round 8: slot-CSR.
// Each node owns 64 fixed slots; the counting atomic's return value IS the
// slot index, so count+scatter fuse into k_prep and scan/scatter kernels
// vanish. 9 dispatches: memset, k_prep, [agg,gemm]x2, proj, agg64, gemm64.

#define NFEAT 128
#define SLOTS 64

typedef __attribute__((ext_vector_type(8))) short short8;
typedef __attribute__((ext_vector_type(4))) float floatx4;

__device__ __forceinline__ float bf_lo(unsigned u) { return __uint_as_float(u << 16); }
__device__ __forceinline__ float bf_hi(unsigned u) { return __uint_as_float(u & 0xffff0000u); }
__device__ __forceinline__ ushort f2bf(float f) {
    __hip_bfloat16 h = __float2bfloat16(f);
    return *(ushort*)&h;
}
__device__ __forceinline__ unsigned pack2(float a, float b) {
    return (unsigned)f2bf(a) | ((unsigned)f2bf(b) << 16);
}

// ---------------- combined prep: count+slot-scatter + x->bf16 + weight prep ----------------

__global__ __launch_bounds__(256) void k_prep(
    const int* __restrict__ dst, const int* __restrict__ src,
    int* __restrict__ deg, int* __restrict__ csr,
    int E, int NN,
    const float* __restrict__ X, ushort* __restrict__ X16, int n2,
    const float* __restrict__ Ws0, const float* __restrict__ Wn0,
    const float* __restrict__ Ws1, const float* __restrict__ Wn1,
    const float* __restrict__ Ws2, const float* __restrict__ Wn2,
    ushort* __restrict__ Wt0, ushort* __restrict__ Wt1, ushort* __restrict__ Wt2,
    int e4b, int cvtb) {
    int b = blockIdx.x, t = threadIdx.x;
    if (b < e4b) {
        int base = (b * 256 + t) * 4;
        if (base + 4 <= E) {
            int4 d4 = *(const int4*)(dst + base);
            int4 s4 = *(const int4*)(src + base);
            int r0 = atomicAdd(&deg[d4.x], 1);
            int r1 = atomicAdd(&deg[d4.y], 1);
            int r2 = atomicAdd(&deg[d4.z], 1);
            int r3 = atomicAdd(&deg[d4.w], 1);
            if (r0 < SLOTS) csr[(d4.x << 6) + r0] = s4.x;
            if (r1 < SLOTS) csr[(d4.y << 6) + r1] = s4.y;
            if (r2 < SLOTS) csr[(d4.z << 6) + r2] = s4.z;
            if (r3 < SLOTS) csr[(d4.w << 6) + r3] = s4.w;
        } else {
            for (int e = base; e < E; ++e) {
                int d = dst[e];
                int r = atomicAdd(&deg[d], 1);
                if (r < SLOTS) csr[(d << 6) + r] = src[e];
            }
        }
    } else if (b < e4b + cvtb) {
        int i = (b - e4b) * 256 + t;
        if (i < n2) {
            float2 v = ((const float2*)X)[i];
            ((unsigned*)X16)[i] = pack2(v.x, v.y);
        }
    } else {
        int idx = (b - e4b - cvtb) * 256 + t;
        if (idx < 32768) {
            int n = idx >> 8, k = idx & 255;
            Wt0[idx] = f2bf(k < 128 ? Ws0[k * 128 + n] : Wn0[(k - 128) * 128 + n]);
        } else if (idx < 65536) {
            int l = idx - 32768, n = l >> 8, k = l & 255;
            Wt1[l] = f2bf(k < 128 ? Ws1[k * 128 + n] : Wn1[(k - 128) * 128 + n]);
        } else if (idx < 81920) {
            int l = idx - 65536, n = l >> 8, k = l & 255;
            Wt2[l] = f2bf(k < 128 ? Ws2[k * 64 + n] : Wn2[(k - 128) * 64 + n]);
        }
    }
}

// ---------------- mean aggregation: one wave per node, slot bins, 4x/2x/1x ladder ----------------

template <int FEAT, bool OUT_BF16>
__global__ __launch_bounds__(256) void k_agg_t(const ushort* __restrict__ H,
                                               const int* __restrict__ deg,
                                               const int* __restrict__ csr,
                                               void* __restrict__ outp, int NN) {
    constexpr int LPR = FEAT / 8;   // lanes per row (16B chunks of 8 bf16)
    constexpr int EPG = 64 / LPR;   // edges per wave-iteration
    int node = (blockIdx.x * 256 + threadIdx.x) >> 6;
    if (node >= NN) return;
    int lane = threadIdx.x & 63;
    int sub = lane / LPR, fl = lane % LPR;
    int dd = deg[node];
    int d = (dd < SLOTS) ? dd : SLOTS;
    const int* slot = csr + (node << 6);
    float acc[8] = {};
    int e = sub;
    for (; e + 3 * EPG < d; e += 4 * EPG) {   // 4 rows in flight
        int r0 = slot[e], r1 = slot[e + EPG], r2 = slot[e + 2 * EPG], r3 = slot[e + 3 * EPG];
        uint4 v0 = *(const uint4*)(H + (size_t)r0 * FEAT + fl * 8);
        uint4 v1 = *(const uint4*)(H + (size_t)r1 * FEAT + fl * 8);
        uint4 v2 = *(const uint4*)(H + (size_t)r2 * FEAT + fl * 8);
        uint4 v3 = *(const uint4*)(H + (size_t)r3 * FEAT + fl * 8);
        acc[0] += bf_lo(v0.x) + bf_lo(v1.x) + bf_lo(v2.x) + bf_lo(v3.x);
        acc[1] += bf_hi(v0.x) + bf_hi(v1.x) + bf_hi(v2.x) + bf_hi(v3.x);
        acc[2] += bf_lo(v0.y) + bf_lo(v1.y) + bf_lo(v2.y) + bf_lo(v3.y);
        acc[3] += bf_hi(v0.y) + bf_hi(v1.y) + bf_hi(v2.y) + bf_hi(v3.y);
        acc[4] += bf_lo(v0.z) + bf_lo(v1.z) + bf_lo(v2.z) + bf_lo(v3.z);
        acc[5] += bf_hi(v0.z) + bf_hi(v1.z) + bf_hi(v2.z) + bf_hi(v3.z);
        acc[6] += bf_lo(v0.w) + bf_lo(v1.w) + bf_lo(v2.w) + bf_lo(v3.w);
        acc[7] += bf_hi(v0.w) + bf_hi(v1.w) + bf_hi(v2.w) + bf_hi(v3.w);
    }
    for (; e + EPG < d; e += 2 * EPG) {       // 2 rows in flight
        int r0 = slot[e], r1 = slot[e + EPG];
        uint4 v0 = *(const uint4*)(H + (size_t)r0 * FEAT + fl * 8);
        uint4 v1 = *(const uint4*)(H + (size_t)r1 * FEAT + fl * 8);
        acc[0] += bf_lo(v0.x) + bf_lo(v1.x); acc[1] += bf_hi(v0.x) + bf_hi(v1.x);
        acc[2] += bf_lo(v0.y) + bf_lo(v1.y); acc[3] += bf_hi(v0.y) + bf_hi(v1.y);
        acc[4] += bf_lo(v0.z) + bf_lo(v1.z); acc[5] += bf_hi(v0.z) + bf_hi(v1.z);
        acc[6] += bf_lo(v0.w) + bf_lo(v1.w); acc[7] += bf_hi(v0.w) + bf_hi(v1.w);
    }
    for (; e < d; e += EPG) {
        int r = slot[e];
        uint4 v = *(const uint4*)(H + (size_t)r * FEAT + fl * 8);
        acc[0] += bf_lo(v.x); acc[1] += bf_hi(v.x);
        acc[2] += bf_lo(v.y); acc[3] += bf_hi(v.y);
        acc[4] += bf_lo(v.z); acc[5] += bf_hi(v.z);
        acc[6] += bf_lo(v.w); acc[7] += bf_hi(v.w);
    }
#pragma unroll
    for (int off = LPR; off < 64; off <<= 1)
#pragma unroll
        for (int i = 0; i < 8; ++i) acc[i] += __shfl_xor(acc[i], off, 64);
    if (sub == 0) {
        float inv = (dd > 0) ? 1.0f / (float)dd : 0.0f;
        if constexpr (OUT_BF16) {
            unsigned u[4];
#pragma unroll
            for (int i = 0; i < 4; ++i)
                u[i] = pack2(acc[2 * i] * inv, acc[2 * i + 1] * inv);
            *(uint4*)((ushort*)outp + (size_t)node * FEAT + fl * 8) =
                make_uint4(u[0], u[1], u[2], u[3]);
        } else {
            float* O = (float*)outp;
            size_t b = (size_t)node * FEAT + fl * 8;
#pragma unroll
            for (int i = 0; i < 8; ++i) O[b + i] = acc[i] * inv;
        }
    }
}

// ---------------- MFMA GEMM ----------------
// C = A @ Wt^T (+bias) (+addin) (+ReLU). SPLIT: A = [Hs | Ag] along K.
// BM=128, BK=32. Waves 2(m) x BN/64(n), wave tile 64x64 of 16x16x32 MFMA.
// LDS rows padded to 40 ushorts (80B) -> conflict-free ds_read_b128.

template <int BN, int NKB, bool SPLIT, bool OUT_BF16>
__global__ __launch_bounds__(64 * 2 * (BN / 64)) void gemm_mfma(
    const ushort* __restrict__ Hs, const ushort* __restrict__ Ag,
    const ushort* __restrict__ Wt, int ldw, const float* __restrict__ bias,
    const float* __restrict__ addin, void* __restrict__ Cout, int M, int relu) {
    constexpr int WN = BN / 64;
    constexpr int NTHR = 64 * 2 * WN;
    constexpr int LDA = 40;
    __shared__ ushort Asl[128 * LDA];
    __shared__ ushort Bsl[BN * LDA];

    int t = threadIdx.x;
    int lane = t & 63;
    int wid = t >> 6;
    int wm = wid & 1, wn = wid >> 1;
    int l15 = lane & 15, quad = lane >> 4;
    int m0 = blockIdx.x * 128;

    floatx4 acc[4][4] = {};

    for (int kb = 0; kb < NKB; ++kb) {
        const ushort* Asrc;
        int kOff;
        if constexpr (SPLIT) {
            Asrc = (kb < NKB / 2) ? Hs : Ag;
            kOff = (kb & (NKB / 2 - 1)) * 32;
        } else {
            Asrc = Hs;
            kOff = kb * 32;
        }
        __syncthreads();
#pragma unroll
        for (int id = t; id < 128 * 4; id += NTHR) {
            int r = id >> 2, p = id & 3;
            uint4 v = make_uint4(0, 0, 0, 0);
            if (m0 + r < M) v = *(const uint4*)(Asrc + (size_t)(m0 + r) * NFEAT + kOff + p * 8);
            *(uint4*)(&Asl[r * LDA + p * 8]) = v;
        }
#pragma unroll
        for (int id = t; id < BN * 4; id += NTHR) {
            int r = id >> 2, p = id & 3;
            uint4 v = *(const uint4*)(Wt + (size_t)r * ldw + kb * 32 + p * 8);
            *(uint4*)(&Bsl[r * LDA + p * 8]) = v;
        }
        __syncthreads();

        short8 a[4], b[4];
#pragma unroll
        for (int mt = 0; mt < 4; ++mt)
            a[mt] = *(const short8*)(&Asl[(wm * 64 + mt * 16 + l15) * LDA + quad * 8]);
#pragma unroll
        for (int nt = 0; nt < 4; ++nt)
            b[nt] = *(const short8*)(&Bsl[(wn * 64 + nt * 16 + l15) * LDA + quad * 8]);
#pragma unroll
        for (int mt = 0; mt < 4; ++mt)
#pragma unroll
            for (int nt = 0; nt < 4; ++nt)
                acc[mt][nt] = __builtin_amdgcn_mfma_f32_16x16x32_bf16(a[mt], b[nt], acc[mt][nt], 0, 0, 0);
    }

#pragma unroll
    for (int mt = 0; mt < 4; ++mt) {
        int mbase = m0 + wm * 64 + mt * 16 + quad * 4;
#pragma unroll
        for (int nt = 0; nt < 4; ++nt) {
            int col = wn * 64 + nt * 16 + l15;
            float bv = bias ? bias[col] : 0.0f;
#pragma unroll
            for (int r = 0; r < 4; ++r) {
                int m = mbase + r;
                if (m < M) {
                    float v = acc[mt][nt][r] + bv;
                    if (addin) v += addin[(size_t)m * BN + col];
                    if (relu) v = fmaxf(v, 0.f);
                    if constexpr (OUT_BF16) {
                        ((unsigned short*)Cout)[(size_t)m * BN + col] = f2bf(v);
                    } else {
                        ((float*)Cout)[(size_t)m * BN + col] = v;
                    }
                }
            }
        }
    }
}

// ---------------- launch ----------------

static inline size_t align_up(size_t x) { return (x + 255) & ~(size_t)255; }

extern "C" void kernel_launch(void* const* d_in, const int* in_sizes, int n_in,
                              void* d_out, int out_size, void* d_ws, size_t ws_size,
                              hipStream_t stream) {
    const float* x   = (const float*)d_in[0];
    const int*   src = (const int*)d_in[1];
    const int*   dst = (const int*)d_in[2];
    const float* Ws0 = (const float*)d_in[3];
    const float* Wn0 = (const float*)d_in[4];
    const float* b0  = (const float*)d_in[5];
    const float* Ws1 = (const float*)d_in[6];
    const float* Wn1 = (const float*)d_in[7];
    const float* b1  = (const float*)d_in[8];
    const float* Ws2 = (const float*)d_in[9];
    const float* Wn2 = (const float*)d_in[10];
    const float* b2  = (const float*)d_in[11];
    float* out = (float*)d_out;

    const int NN = in_sizes[0] / NFEAT;   // 50000
    const int E  = in_sizes[1];           // 800000

    char* w = (char*)d_ws;
    ushort* X16  = (ushort*)w; w += align_up((size_t)NN * NFEAT * 2);
    ushort* Ha   = (ushort*)w; w += align_up((size_t)NN * NFEAT * 2);
    ushort* Hb   = (ushort*)w; w += align_up((size_t)NN * NFEAT * 2);
    ushort* AGG  = (ushort*)w; w += align_up((size_t)NN * NFEAT * 2);
    ushort* Wt0  = (ushort*)w; w += align_up((size_t)128 * 256 * 2);
    ushort* Wt1  = (ushort*)w; w += align_up((size_t)128 * 256 * 2);
    ushort* Wt2  = (ushort*)w; w += align_up((size_t)64 * 256 * 2);
    int* deg     = (int*)w;    w += align_up((size_t)NN * 4);
    int* csr     = (int*)w;    w += align_up((size_t)NN * SLOTS * 4);   // 12.8 MB slot bins

    // aliased scratch (lifetimes disjoint):
    ushort* G2  = X16;           // layer-2 projected table, after X16 dead
    float*  A2  = (float*)AGG;   // layer-2 fp32 aggregate, after AGG dead

    hipMemsetAsync(deg, 0, (size_t)NN * 4, stream);

    const int e4b  = (E / 4 + 255) / 256;
    const int n2   = NN * NFEAT / 2;
    const int cvtb = (n2 + 255) / 256;
    const int wb   = (81920 + 255) / 256;

    k_prep<<<e4b + cvtb + wb, 256, 0, stream>>>(
        dst, src, deg, csr, E, NN, x, X16, n2,
        Ws0, Wn0, Ws1, Wn1, Ws2, Wn2, Wt0, Wt1, Wt2, e4b, cvtb);

    const int ab = (NN * 64 + 255) / 256;
    const int gm = (NN + 127) / 128;

    // layer 0: X16 -> Ha (ReLU)
    k_agg_t<128, true><<<ab, 256, 0, stream>>>(X16, deg, csr, AGG, NN);
    gemm_mfma<128, 8, true, true><<<gm, 256, 0, stream>>>(X16, AGG, Wt0, 256, b0, nullptr, Ha, NN, 1);

    // layer 1: Ha -> Hb (ReLU)
    k_agg_t<128, true><<<ab, 256, 0, stream>>>(Ha, deg, csr, AGG, NN);
    gemm_mfma<128, 8, true, true><<<gm, 256, 0, stream>>>(Ha, AGG, Wt1, 256, b1, nullptr, Hb, NN, 1);

    // layer 2: agg(Hb)@Wn2 == agg(Hb@Wn2) -> 64-wide gather table
    gemm_mfma<64, 4, false, true><<<gm, 128, 0, stream>>>(Hb, nullptr, Wt2 + 128, 256, nullptr, nullptr, G2, NN, 0);
    k_agg_t<64, false><<<ab, 256, 0, stream>>>(G2, deg, csr, A2, NN);
    gemm_mfma<64, 4, false, false><<<gm, 128, 0, stream>>>(Hb, nullptr, Wt2, 256, b2, A2, out, NN, 0);
}